// Round 4
// baseline (3781.038 us; speedup 1.0000x reference)
//
#include <hip/hip_runtime.h>
#include <cstdint>
#include <cstddef>

typedef unsigned short u16;
typedef unsigned int   u32;

#define B_    2
#define T_    4096
#define HID   2048
#define NH    6
#define DK    256
#define DV    512
#define KD    1536   // NH*DK
#define VD    3072   // NH*DV
#define MROWS 8192   // B_*T_

typedef short short8 __attribute__((ext_vector_type(8)));
typedef float f32x4v __attribute__((ext_vector_type(4)));

__device__ __forceinline__ float bf2f(u16 u){
  union { u32 i; float f; } v; v.i = ((u32)u) << 16; return v.f;
}
__device__ __forceinline__ u16 f2bf(float f){
  union { float f; u32 i; } v; v.f = f;
  u32 r = v.i + 0x7fffu + ((v.i >> 16) & 1u);
  return (u16)(r >> 16);
}
__device__ __forceinline__ u32 pack2(float a, float b){
  return (u32)f2bf(a) | ((u32)f2bf(b) << 16);
}
__device__ __forceinline__ void unpack8(uint4 p, float* f){
  f[0]=bf2f((u16)(p.x&0xffffu)); f[1]=bf2f((u16)(p.x>>16));
  f[2]=bf2f((u16)(p.y&0xffffu)); f[3]=bf2f((u16)(p.y>>16));
  f[4]=bf2f((u16)(p.z&0xffffu)); f[5]=bf2f((u16)(p.z>>16));
  f[6]=bf2f((u16)(p.w&0xffffu)); f[7]=bf2f((u16)(p.w>>16));
}

// ---------------------------------------------------------------------------
// Transpose + downcast: in f32 [R][C] -> out bf16 [C][R]. Grid (C/64, R/64).
// ---------------------------------------------------------------------------
__global__ __launch_bounds__(256)
void transpose_f2b(const float* __restrict__ in, u16* __restrict__ out, int R, int C)
{
  __shared__ u16 tile[64][72];  // pad to dodge bank conflicts
  int tid = threadIdx.x;
  int lx = tid & 63, ly = tid >> 6;
  int x = blockIdx.x*64 + lx;
  #pragma unroll
  for (int i = 0; i < 64; i += 4)
    tile[i+ly][lx] = f2bf(in[(size_t)(blockIdx.y*64 + i + ly)*C + x]);
  __syncthreads();
  int x2 = blockIdx.y*64 + lx;
  #pragma unroll
  for (int i = 0; i < 64; i += 4)
    out[(size_t)(blockIdx.x*64 + i + ly)*R + x2] = tile[lx][i+ly];
}

// ---------------------------------------------------------------------------
// GEMM variant 1: A bf16, Bt bf16, C bf16 (m97 structure). C[M,N] = A * Bt^T.
// 128x128 tile, BK=32, 256 thr (4 waves 2x2), mfma 16x16x32_bf16.
// ---------------------------------------------------------------------------
__global__ __launch_bounds__(256)
void gemm_bt(const u16* __restrict__ A, const u16* __restrict__ Bt, u16* __restrict__ C,
             int M, int N, int K)
{
  __shared__ __align__(16) u16 As[128*32];
  __shared__ __align__(16) u16 Bs[128*32];
  const int tid  = threadIdx.x;
  const int wave = tid >> 6;
  const int lane = tid & 63;
  const int bm = blockIdx.y, bn = blockIdx.x;
  const int fr = lane & 15, fq = lane >> 4;
  const int wm = (wave >> 1) * 64, wn = (wave & 1) * 64;
  const int srow = tid >> 2, spart = tid & 3;
  const u16* Abase = A  + (size_t)bm * 128 * K;
  const u16* Bbase = Bt + (size_t)bn * 128 * K;

  f32x4v acc[4][4];
  #pragma unroll
  for (int i=0;i<4;i++)
    #pragma unroll
    for (int j=0;j<4;j++){ f32x4v z = {0.f,0.f,0.f,0.f}; acc[i][j] = z; }

  for (int k0 = 0; k0 < K; k0 += 32){
    #pragma unroll
    for (int c = 0; c < 2; ++c){
      const u16* ga = Abase + (size_t)(c*64 + srow) * K + k0 + spart*8;
      const u16* gb = Bbase + (size_t)(c*64 + srow) * K + k0 + spart*8;
      u16* la = &As[(c*64 + wave*16) * 32];  // wave-uniform base; lane i -> +i*16B
      u16* lb = &Bs[(c*64 + wave*16) * 32];
      __builtin_amdgcn_global_load_lds((const __attribute__((address_space(1))) void*)ga,
                                       (__attribute__((address_space(3))) void*)la, 16, 0, 0);
      __builtin_amdgcn_global_load_lds((const __attribute__((address_space(1))) void*)gb,
                                       (__attribute__((address_space(3))) void*)lb, 16, 0, 0);
    }
    __syncthreads();
    short8 af[4], bfm[4];
    #pragma unroll
    for (int mi=0;mi<4;mi++) af[mi]  = *(const short8*)&As[(wm + mi*16 + fr)*32 + fq*8];
    #pragma unroll
    for (int ni=0;ni<4;ni++) bfm[ni] = *(const short8*)&Bs[(wn + ni*16 + fr)*32 + fq*8];
    #pragma unroll
    for (int mi=0;mi<4;mi++)
      #pragma unroll
      for (int ni=0;ni<4;ni++)
        acc[mi][ni] = __builtin_amdgcn_mfma_f32_16x16x32_bf16(af[mi], bfm[ni], acc[mi][ni], 0, 0, 0);
    __syncthreads();
  }

  // C/D layout (m89/m91): col = lane&15, row = (lane>>4)*4 + reg
  #pragma unroll
  for (int mi=0;mi<4;mi++){
    #pragma unroll
    for (int ni=0;ni<4;ni++){
      int r0 = bm*128 + wm + mi*16 + fq*4;
      int c0 = bn*128 + wn + ni*16 + fr;
      #pragma unroll
      for (int rr=0;rr<4;rr++)
        C[(size_t)(r0+rr)*N + c0] = f2bf(acc[mi][ni][rr]);
    }
  }
}

// ---------------------------------------------------------------------------
// GEMM variant 2: A f32 (cvt to bf16 during LDS staging), Bt bf16, C bf16.
// ---------------------------------------------------------------------------
__global__ __launch_bounds__(256)
void gemm_f32a_bt(const float* __restrict__ A, const u16* __restrict__ Bt, u16* __restrict__ C,
                  int M, int N, int K)
{
  __shared__ __align__(16) u16 As[128*32];
  __shared__ __align__(16) u16 Bs[128*32];
  const int tid  = threadIdx.x;
  const int wave = tid >> 6;
  const int lane = tid & 63;
  const int bm = blockIdx.y, bn = blockIdx.x;
  const int fr = lane & 15, fq = lane >> 4;
  const int wm = (wave >> 1) * 64, wn = (wave & 1) * 64;
  const int srow = tid >> 2, spart = tid & 3;
  const float* Abase = A + (size_t)bm * 128 * K;
  const u16*   Bbase = Bt + (size_t)bn * 128 * K;

  f32x4v acc[4][4];
  #pragma unroll
  for (int i=0;i<4;i++)
    #pragma unroll
    for (int j=0;j<4;j++){ f32x4v z = {0.f,0.f,0.f,0.f}; acc[i][j] = z; }

  for (int k0 = 0; k0 < K; k0 += 32){
    #pragma unroll
    for (int c = 0; c < 2; ++c){
      // B: async DMA (bf16 weights)
      const u16* gb = Bbase + (size_t)(c*64 + srow) * K + k0 + spart*8;
      u16* lb = &Bs[(c*64 + wave*16) * 32];
      __builtin_amdgcn_global_load_lds((const __attribute__((address_space(1))) void*)gb,
                                       (__attribute__((address_space(3))) void*)lb, 16, 0, 0);
      // A: f32 load -> bf16 cvt -> LDS (identical layout to gemm_bt)
      const float4* ga = (const float4*)(Abase + (size_t)(c*64 + srow) * K + k0 + spart*8);
      float4 v0 = ga[0], v1 = ga[1];
      uint4 pk;
      pk.x = pack2(v0.x, v0.y); pk.y = pack2(v0.z, v0.w);
      pk.z = pack2(v1.x, v1.y); pk.w = pack2(v1.z, v1.w);
      *(uint4*)&As[(c*64 + srow)*32 + spart*8] = pk;
    }
    __syncthreads();
    short8 af[4], bfm[4];
    #pragma unroll
    for (int mi=0;mi<4;mi++) af[mi]  = *(const short8*)&As[(wm + mi*16 + fr)*32 + fq*8];
    #pragma unroll
    for (int ni=0;ni<4;ni++) bfm[ni] = *(const short8*)&Bs[(wn + ni*16 + fr)*32 + fq*8];
    #pragma unroll
    for (int mi=0;mi<4;mi++)
      #pragma unroll
      for (int ni=0;ni<4;ni++)
        acc[mi][ni] = __builtin_amdgcn_mfma_f32_16x16x32_bf16(af[mi], bfm[ni], acc[mi][ni], 0, 0, 0);
    __syncthreads();
  }

  #pragma unroll
  for (int mi=0;mi<4;mi++){
    #pragma unroll
    for (int ni=0;ni<4;ni++){
      int r0 = bm*128 + wm + mi*16 + fq*4;
      int c0 = bn*128 + wn + ni*16 + fr;
      #pragma unroll
      for (int rr=0;rr<4;rr++)
        C[(size_t)(r0+rr)*N + c0] = f2bf(acc[mi][ni][rr]);
    }
  }
}

// ---------------------------------------------------------------------------
// GEMM variant 3: A bf16, Bt bf16, C **f32** (for the final output projection —
// d_out is float32 per the reference's output dtype).
// ---------------------------------------------------------------------------
__global__ __launch_bounds__(256)
void gemm_bt_f32out(const u16* __restrict__ A, const u16* __restrict__ Bt, float* __restrict__ C,
                    int M, int N, int K)
{
  __shared__ __align__(16) u16 As[128*32];
  __shared__ __align__(16) u16 Bs[128*32];
  const int tid  = threadIdx.x;
  const int wave = tid >> 6;
  const int lane = tid & 63;
  const int bm = blockIdx.y, bn = blockIdx.x;
  const int fr = lane & 15, fq = lane >> 4;
  const int wm = (wave >> 1) * 64, wn = (wave & 1) * 64;
  const int srow = tid >> 2, spart = tid & 3;
  const u16* Abase = A  + (size_t)bm * 128 * K;
  const u16* Bbase = Bt + (size_t)bn * 128 * K;

  f32x4v acc[4][4];
  #pragma unroll
  for (int i=0;i<4;i++)
    #pragma unroll
    for (int j=0;j<4;j++){ f32x4v z = {0.f,0.f,0.f,0.f}; acc[i][j] = z; }

  for (int k0 = 0; k0 < K; k0 += 32){
    #pragma unroll
    for (int c = 0; c < 2; ++c){
      const u16* ga = Abase + (size_t)(c*64 + srow) * K + k0 + spart*8;
      const u16* gb = Bbase + (size_t)(c*64 + srow) * K + k0 + spart*8;
      u16* la = &As[(c*64 + wave*16) * 32];
      u16* lb = &Bs[(c*64 + wave*16) * 32];
      __builtin_amdgcn_global_load_lds((const __attribute__((address_space(1))) void*)ga,
                                       (__attribute__((address_space(3))) void*)la, 16, 0, 0);
      __builtin_amdgcn_global_load_lds((const __attribute__((address_space(1))) void*)gb,
                                       (__attribute__((address_space(3))) void*)lb, 16, 0, 0);
    }
    __syncthreads();
    short8 af[4], bfm[4];
    #pragma unroll
    for (int mi=0;mi<4;mi++) af[mi]  = *(const short8*)&As[(wm + mi*16 + fr)*32 + fq*8];
    #pragma unroll
    for (int ni=0;ni<4;ni++) bfm[ni] = *(const short8*)&Bs[(wn + ni*16 + fr)*32 + fq*8];
    #pragma unroll
    for (int mi=0;mi<4;mi++)
      #pragma unroll
      for (int ni=0;ni<4;ni++)
        acc[mi][ni] = __builtin_amdgcn_mfma_f32_16x16x32_bf16(af[mi], bfm[ni], acc[mi][ni], 0, 0, 0);
    __syncthreads();
  }

  #pragma unroll
  for (int mi=0;mi<4;mi++){
    #pragma unroll
    for (int ni=0;ni<4;ni++){
      int r0 = bm*128 + wm + mi*16 + fq*4;
      int c0 = bn*128 + wn + ni*16 + fr;
      #pragma unroll
      for (int rr=0;rr<4;rr++)
        C[(size_t)(r0+rr)*N + c0] = acc[mi][ni][rr];
    }
  }
}

// ---------------------------------------------------------------------------
// Wa/Wb projections (N=6) + softplus/sigmoid -> g_decay, beta. All f32 in.
// ---------------------------------------------------------------------------
__global__ __launch_bounds__(64)
void proj_ab(const float* __restrict__ hs, const float* __restrict__ Wa, const float* __restrict__ Wb,
             const float* __restrict__ A_log, const float* __restrict__ dt_b,
             float* __restrict__ gdec, float* __restrict__ betav)
{
  int r = blockIdx.x;
  int lane = threadIdx.x;
  float hv[32];
  const float4* hp = (const float4*)(hs + (size_t)r*HID + lane*32);
  #pragma unroll
  for (int q=0;q<8;q++){ float4 v = hp[q]; hv[q*4]=v.x; hv[q*4+1]=v.y; hv[q*4+2]=v.z; hv[q*4+3]=v.w; }
  float a[6] = {0,0,0,0,0,0}, b[6] = {0,0,0,0,0,0};
  {
    const float* wp = Wa + (size_t)lane*192;
    #pragma unroll
    for (int u=0; u<48; ++u){
      float4 wv = *(const float4*)(wp + u*4);
      float wf[4] = {wv.x, wv.y, wv.z, wv.w};
      #pragma unroll
      for (int p=0;p<4;p++){ int idx = u*4+p; a[idx%6] += hv[idx/6] * wf[p]; }
    }
  }
  {
    const float* wp = Wb + (size_t)lane*192;
    #pragma unroll
    for (int u=0; u<48; ++u){
      float4 wv = *(const float4*)(wp + u*4);
      float wf[4] = {wv.x, wv.y, wv.z, wv.w};
      #pragma unroll
      for (int p=0;p<4;p++){ int idx = u*4+p; b[idx%6] += hv[idx/6] * wf[p]; }
    }
  }
  #pragma unroll
  for (int off=1; off<64; off<<=1){
    #pragma unroll
    for (int j=0;j<6;j++){ a[j] += __shfl_xor(a[j], off); b[j] += __shfl_xor(b[j], off); }
  }
  if (lane == 0){
    #pragma unroll
    for (int j=0;j<6;j++){
      float da = a[j] + dt_b[j];
      float sp = (da > 15.f) ? da : log1pf(expf(da));
      gdec[(size_t)r*6 + j]  = -expf(A_log[j]) * sp;
      betav[(size_t)r*6 + j] = 1.f / (1.f + expf(-b[j]));
    }
  }
}

// ---------------------------------------------------------------------------
// Causal conv(K=4)+SiLU + per-head l2norm (q: scale=1/16, k: 1).
// ---------------------------------------------------------------------------
__global__ __launch_bounds__(256)
void conv_norm_qk(const u16* __restrict__ x, const float* __restrict__ cw,
                  u16* __restrict__ outp, float scale)
{
  int r = blockIdx.x, h = blockIdx.y;
  int t = r & (T_-1);
  int d = threadIdx.x;
  int colg = h*DK + d;
  float4 wv = *(const float4*)(cw + (size_t)colg*4);
  float w[4] = {wv.x, wv.y, wv.z, wv.w};
  float acc = 0.f;
  #pragma unroll
  for (int i=0;i<4;i++){
    int st = t - 3 + i;
    if (st >= 0) acc += bf2f(x[(size_t)(r-3+i)*KD + colg]) * w[i];
  }
  float yv = acc / (1.f + __expf(-acc));   // silu
  float ss = yv*yv;
  #pragma unroll
  for (int off=1; off<64; off<<=1) ss += __shfl_xor(ss, off);
  __shared__ float red[4];
  if ((threadIdx.x & 63) == 0) red[threadIdx.x>>6] = ss;
  __syncthreads();
  float tot = red[0]+red[1]+red[2]+red[3];
  float out = yv * rsqrtf(tot) * scale;    // l2norm (no eps, per reference)
  outp[(size_t)r*KD + colg] = f2bf(out);
}

// ---------------------------------------------------------------------------
// Causal conv(K=4)+SiLU for v.
// ---------------------------------------------------------------------------
__global__ __launch_bounds__(384)
void conv_v_k(const u16* __restrict__ x, const float* __restrict__ cw, u16* __restrict__ outp)
{
  int r = blockIdx.x;
  int t = r & (T_-1);
  int c8 = threadIdx.x * 8;
  float w[8][4];
  #pragma unroll
  for (int q=0;q<8;q++){
    float4 wv = *(const float4*)(cw + (size_t)c8*4 + q*4);
    w[q][0]=wv.x; w[q][1]=wv.y; w[q][2]=wv.z; w[q][3]=wv.w;
  }
  float acc[8] = {0,0,0,0,0,0,0,0};
  #pragma unroll
  for (int i=0;i<4;i++){
    int st = t-3+i;
    if (st >= 0){
      uint4 xv = *(const uint4*)(x + (size_t)(r-3+i)*VD + c8);
      float xf[8]; unpack8(xv, xf);
      #pragma unroll
      for (int e=0;e<8;e++) acc[e] += xf[e]*w[e][i];
    }
  }
  u32 pk[4];
  #pragma unroll
  for (int e=0;e<8;e+=2){
    float y0 = acc[e]  /(1.f+__expf(-acc[e]));
    float y1 = acc[e+1]/(1.f+__expf(-acc[e+1]));
    pk[e/2] = pack2(y0, y1);
  }
  uint4 o4; o4.x=pk[0]; o4.y=pk[1]; o4.z=pk[2]; o4.w=pk[3];
  *(uint4*)(outp + (size_t)r*VD + c8) = o4;
}

// ---------------------------------------------------------------------------
// Gated delta rule scan. Grid (16 dv-slices, NH, B_), block 256.
// ---------------------------------------------------------------------------
__global__ __launch_bounds__(256)
void scan_k(const u16* __restrict__ qc, const u16* __restrict__ kc, const u16* __restrict__ vc,
            const float* __restrict__ gdec, const float* __restrict__ betav,
            u16* __restrict__ o)
{
  const int slice = blockIdx.x, h = blockIdx.y, b = blockIdx.z;
  const int tid = threadIdx.x;
  const int col = tid >> 3, rg = tid & 7;
  __shared__ __align__(16) float k_lds[16][256];
  __shared__ __align__(16) float q_lds[16][256];
  __shared__ __align__(16) float v_lds[16][32];
  __shared__ float g_lds[16], be_lds[16];
  float4 S[8];
  #pragma unroll
  for (int i=0;i<8;i++) S[i] = make_float4(0.f,0.f,0.f,0.f);
  const int st_tok = tid >> 4, st_e = tid & 15;
  const size_t rb = (size_t)b * T_;

  for (int tb = 0; tb < T_/16; ++tb){
    __syncthreads();
    {
      size_t r = rb + (size_t)tb*16 + st_tok;
      const u16* kp = kc + r*KD + h*DK + st_e*16;
      const u16* qp = qc + r*KD + h*DK + st_e*16;
      float tmp[16];
      uint4 a0 = *(const uint4*)kp, a1 = *(const uint4*)(kp+8);
      unpack8(a0, tmp); unpack8(a1, tmp+8);
      #pragma unroll
      for (int q=0;q<4;q++)
        *(float4*)&k_lds[st_tok][st_e*16 + q*4] = make_float4(tmp[q*4],tmp[q*4+1],tmp[q*4+2],tmp[q*4+3]);
      a0 = *(const uint4*)qp; a1 = *(const uint4*)(qp+8);
      unpack8(a0, tmp); unpack8(a1, tmp+8);
      #pragma unroll
      for (int q=0;q<4;q++)
        *(float4*)&q_lds[st_tok][st_e*16 + q*4] = make_float4(tmp[q*4],tmp[q*4+1],tmp[q*4+2],tmp[q*4+3]);
      const u16* vp = vc + r*VD + h*DV + slice*32 + st_e*2;
      u32 vv = *(const u32*)vp;
      v_lds[st_tok][st_e*2]   = bf2f((u16)(vv & 0xffffu));
      v_lds[st_tok][st_e*2+1] = bf2f((u16)(vv >> 16));
      if (st_e == 0){ g_lds[st_tok] = gdec[r*6 + h]; be_lds[st_tok] = betav[r*6 + h]; }
    }
    __syncthreads();

    for (int s = 0; s < 16; ++s){
      float decay = __expf(g_lds[s]);
      float bta   = be_lds[s];
      float vv    = v_lds[s][col];
      float4 kk[8], qq[8];
      #pragma unroll
      for (int i=0;i<8;i++){
        kk[i] = *(const float4*)&k_lds[s][i*32 + rg*4];
        qq[i] = *(const float4*)&q_lds[s][i*32 + rg*4];
      }
      float p0=0.f,p1=0.f,p2=0.f,p3=0.f;
      #pragma unroll
      for (int i=0;i<8;i++){
        p0 = fmaf(kk[i].x, S[i].x, p0); p1 = fmaf(kk[i].y, S[i].y, p1);
        p2 = fmaf(kk[i].z, S[i].z, p2); p3 = fmaf(kk[i].w, S[i].w, p3);
      }
      float p = (p0+p1)+(p2+p3);
      p += __shfl_xor(p, 1); p += __shfl_xor(p, 2); p += __shfl_xor(p, 4);
      float delta = (vv - decay * p) * bta;
      float o0=0.f,o1=0.f,o2=0.f,o3=0.f;
      #pragma unroll
      for (int i=0;i<8;i++){
        S[i].x = fmaf(S[i].x, decay, kk[i].x * delta);
        S[i].y = fmaf(S[i].y, decay, kk[i].y * delta);
        S[i].z = fmaf(S[i].z, decay, kk[i].z * delta);
        S[i].w = fmaf(S[i].w, decay, kk[i].w * delta);
        o0 = fmaf(qq[i].x, S[i].x, o0); o1 = fmaf(qq[i].y, S[i].y, o1);
        o2 = fmaf(qq[i].z, S[i].z, o2); o3 = fmaf(qq[i].w, S[i].w, o3);
      }
      float oo = (o0+o1)+(o2+o3);
      oo += __shfl_xor(oo, 1); oo += __shfl_xor(oo, 2); oo += __shfl_xor(oo, 4);
      if (rg == 0){
        size_t r = rb + (size_t)tb*16 + s;
        o[r*VD + h*DV + slice*32 + col] = f2bf(oo);
      }
    }
  }
}

// ---------------------------------------------------------------------------
// RMSNorm(512) * norm_weight(f32) * silu(gate) -> y bf16. Grid (MROWS, NH).
// ---------------------------------------------------------------------------
__global__ __launch_bounds__(256)
void norm_gate_k(const u16* __restrict__ o, const u16* __restrict__ gate,
                 const float* __restrict__ nw, u16* __restrict__ y)
{
  int r = blockIdx.x, h = blockIdx.y;
  size_t base = (size_t)r*VD + h*DV;
  int e = threadIdx.x * 2;
  u32 opair = *(const u32*)(o + base + e);
  float ox = bf2f((u16)(opair & 0xffffu)), oy = bf2f((u16)(opair >> 16));
  float ss = ox*ox + oy*oy;
  #pragma unroll
  for (int off=1; off<64; off<<=1) ss += __shfl_xor(ss, off);
  __shared__ float red[4];
  if ((threadIdx.x & 63) == 0) red[threadIdx.x>>6] = ss;
  __syncthreads();
  float ms = (red[0]+red[1]+red[2]+red[3]) * (1.f/512.f);
  float sc = rsqrtf(ms + 1e-5f);
  u32 gv = *(const u32*)(gate + base + e);
  float g0 = bf2f((u16)(gv & 0xffffu)), g1 = bf2f((u16)(gv >> 16));
  float s0 = g0 / (1.f + __expf(-g0)), s1 = g1 / (1.f + __expf(-g1));
  float y0 = ox * sc * nw[e]   * s0;
  float y1 = oy * sc * nw[e+1] * s1;
  *(u32*)(y + base + e) = pack2(y0, y1);
}

// ---------------------------------------------------------------------------
// Workspace plan (163.9 MB; regions reused; fits — rounds 2/3 ran cleanly):
//   WT   12.58 MB : transposed+downcast weight (reused 5x, stream-serial)
//   bufA 50.33 MB : q_lin | k_lin  ->  vcp  ->  y
//   bufB 50.33 MB : v_lin          ->  op (bf16)
//   bufC 50.33 MB : qc | kc        ->  gatep
//   gdec/betav 0.4 MB
// ---------------------------------------------------------------------------
extern "C" void kernel_launch(void* const* d_in, const int* in_sizes, int n_in,
                              void* d_out, int out_size, void* d_ws, size_t ws_size,
                              hipStream_t stream)
{
  const float* hs    = (const float*)d_in[0];
  const float* Wq    = (const float*)d_in[1];
  const float* Wk    = (const float*)d_in[2];
  const float* Wv    = (const float*)d_in[3];
  const float* Wa    = (const float*)d_in[4];
  const float* Wb    = (const float*)d_in[5];
  const float* Wg    = (const float*)d_in[6];
  const float* Wo    = (const float*)d_in[7];
  const float* cwq   = (const float*)d_in[8];
  const float* cwk   = (const float*)d_in[9];
  const float* cwv   = (const float*)d_in[10];
  const float* A_log = (const float*)d_in[11];
  const float* dt_b  = (const float*)d_in[12];
  const float* nw    = (const float*)d_in[13];
  float* out = (float*)d_out;   // reference output dtype is float32

  char* wsb = (char*)d_ws;
  size_t off = 0;
  auto alloc = [&](size_t bytes)->char* {
    char* p = wsb + off; off += (bytes + 255) & ~(size_t)255; return p;
  };
  u16* WT   = (u16*)alloc((size_t)HID*VD*2);
  u16* bufA = (u16*)alloc((size_t)MROWS*VD*2);
  u16* bufB = (u16*)alloc((size_t)MROWS*VD*2);
  u16* bufC = (u16*)alloc((size_t)MROWS*VD*2);
  float* gdec  = (float*)alloc((size_t)MROWS*NH*4);
  float* betav = (float*)alloc((size_t)MROWS*NH*4);

  u16* q_lin = bufA;
  u16* k_lin = bufA + (size_t)MROWS*KD;
  u16* v_lin = bufB;
  u16* qc    = bufC;
  u16* kc    = bufC + (size_t)MROWS*KD;
  u16* vcp   = bufA;          // after q/k convs consume q_lin/k_lin
  u16* op    = bufB;          // after v conv consumes v_lin
  u16* gatep = bufC;          // after scan consumes qc/kc
  u16* yp    = bufA;          // after scan consumes vcp

  dim3 blk256(256);

  // q projection
  transpose_f2b<<<dim3(KD/64, HID/64), blk256, 0, stream>>>(Wq, WT, HID, KD);
  gemm_f32a_bt<<<dim3(KD/128, MROWS/128), blk256, 0, stream>>>(hs, WT, q_lin, MROWS, KD, HID);
  // k projection
  transpose_f2b<<<dim3(KD/64, HID/64), blk256, 0, stream>>>(Wk, WT, HID, KD);
  gemm_f32a_bt<<<dim3(KD/128, MROWS/128), blk256, 0, stream>>>(hs, WT, k_lin, MROWS, KD, HID);
  // v projection
  transpose_f2b<<<dim3(VD/64, HID/64), blk256, 0, stream>>>(Wv, WT, HID, VD);
  gemm_f32a_bt<<<dim3(VD/128, MROWS/128), blk256, 0, stream>>>(hs, WT, v_lin, MROWS, VD, HID);
  // a/b projections + activations
  proj_ab<<<dim3(MROWS), dim3(64), 0, stream>>>(hs, Wa, Wb, A_log, dt_b, gdec, betav);

  // convs (+ l2norm for q/k; q also * dk^-0.5). q,k before v (vcp overwrites bufA).
  conv_norm_qk<<<dim3(MROWS, NH), blk256, 0, stream>>>(q_lin, cwq, qc, 0.0625f);
  conv_norm_qk<<<dim3(MROWS, NH), blk256, 0, stream>>>(k_lin, cwk, kc, 1.0f);
  conv_v_k<<<dim3(MROWS), dim3(384), 0, stream>>>(v_lin, cwv, vcp);

  // gated delta rule scan -> op (bf16, overwrites v_lin region)
  scan_k<<<dim3(16, NH, B_), blk256, 0, stream>>>(qc, kc, vcp, gdec, betav, op);

  // gate projection (into bufC, now free)
  transpose_f2b<<<dim3(VD/64, HID/64), blk256, 0, stream>>>(Wg, WT, HID, VD);
  gemm_f32a_bt<<<dim3(VD/128, MROWS/128), blk256, 0, stream>>>(hs, WT, gatep, MROWS, VD, HID);

  // RMSNorm * nw * silu(gate) -> y (into bufA, now free)
  norm_gate_k<<<dim3(MROWS, NH), blk256, 0, stream>>>(op, gatep, nw, yp);

  // output projection: out(f32) = y @ Wo  (Wo [VD][HID] -> WoT [HID][VD])
  transpose_f2b<<<dim3(HID/64, VD/64), blk256, 0, stream>>>(Wo, WT, VD, HID);
  gemm_bt_f32out<<<dim3(HID/128, MROWS/128), blk256, 0, stream>>>(yp, WT, out, MROWS, HID, VD);
}

// Round 5
// 3618.661 us; speedup vs baseline: 1.0449x; 1.0449x over previous
//
#include <hip/hip_runtime.h>
#include <cstdint>
#include <cstddef>

typedef unsigned short u16;
typedef unsigned int   u32;

#define B_    2
#define T_    4096
#define HID   2048
#define NH    6
#define DK    256
#define DV    512
#define KD    1536   // NH*DK
#define VD    3072   // NH*DV
#define MROWS 8192   // B_*T_

typedef short short8 __attribute__((ext_vector_type(8)));
typedef float f32x4v __attribute__((ext_vector_type(4)));

__device__ __forceinline__ float bf2f(u16 u){
  union { u32 i; float f; } v; v.i = ((u32)u) << 16; return v.f;
}
__device__ __forceinline__ u16 f2bf(float f){
  union { float f; u32 i; } v; v.f = f;
  u32 r = v.i + 0x7fffu + ((v.i >> 16) & 1u);
  return (u16)(r >> 16);
}
__device__ __forceinline__ u32 pack2(float a, float b){
  return (u32)f2bf(a) | ((u32)f2bf(b) << 16);
}
__device__ __forceinline__ void unpack8(uint4 p, float* f){
  f[0]=bf2f((u16)(p.x&0xffffu)); f[1]=bf2f((u16)(p.x>>16));
  f[2]=bf2f((u16)(p.y&0xffffu)); f[3]=bf2f((u16)(p.y>>16));
  f[4]=bf2f((u16)(p.z&0xffffu)); f[5]=bf2f((u16)(p.z>>16));
  f[6]=bf2f((u16)(p.w&0xffffu)); f[7]=bf2f((u16)(p.w>>16));
}

// ---------------------------------------------------------------------------
// Transpose + downcast: in f32 [R][C] -> out bf16 [C][R]. Grid (C/64, R/64).
// ---------------------------------------------------------------------------
__global__ __launch_bounds__(256)
void transpose_f2b(const float* __restrict__ in, u16* __restrict__ out, int R, int C)
{
  __shared__ u16 tile[64][72];
  int tid = threadIdx.x;
  int lx = tid & 63, ly = tid >> 6;
  int x = blockIdx.x*64 + lx;
  #pragma unroll
  for (int i = 0; i < 64; i += 4)
    tile[i+ly][lx] = f2bf(in[(size_t)(blockIdx.y*64 + i + ly)*C + x]);
  __syncthreads();
  int x2 = blockIdx.y*64 + lx;
  #pragma unroll
  for (int i = 0; i < 64; i += 4)
    out[(size_t)(blockIdx.x*64 + i + ly)*R + x2] = tile[lx][i+ly];
}

// ---------------------------------------------------------------------------
// GEMM variant 1: A bf16, Bt bf16, C bf16 (m97 structure). C[M,N] = A * Bt^T.
// ---------------------------------------------------------------------------
__global__ __launch_bounds__(256)
void gemm_bt(const u16* __restrict__ A, const u16* __restrict__ Bt, u16* __restrict__ C,
             int M, int N, int K)
{
  __shared__ __align__(16) u16 As[128*32];
  __shared__ __align__(16) u16 Bs[128*32];
  const int tid  = threadIdx.x;
  const int wave = tid >> 6;
  const int lane = tid & 63;
  const int bm = blockIdx.y, bn = blockIdx.x;
  const int fr = lane & 15, fq = lane >> 4;
  const int wm = (wave >> 1) * 64, wn = (wave & 1) * 64;
  const int srow = tid >> 2, spart = tid & 3;
  const u16* Abase = A  + (size_t)bm * 128 * K;
  const u16* Bbase = Bt + (size_t)bn * 128 * K;

  f32x4v acc[4][4];
  #pragma unroll
  for (int i=0;i<4;i++)
    #pragma unroll
    for (int j=0;j<4;j++){ f32x4v z = {0.f,0.f,0.f,0.f}; acc[i][j] = z; }

  for (int k0 = 0; k0 < K; k0 += 32){
    #pragma unroll
    for (int c = 0; c < 2; ++c){
      const u16* ga = Abase + (size_t)(c*64 + srow) * K + k0 + spart*8;
      const u16* gb = Bbase + (size_t)(c*64 + srow) * K + k0 + spart*8;
      u16* la = &As[(c*64 + wave*16) * 32];
      u16* lb = &Bs[(c*64 + wave*16) * 32];
      __builtin_amdgcn_global_load_lds((const __attribute__((address_space(1))) void*)ga,
                                       (__attribute__((address_space(3))) void*)la, 16, 0, 0);
      __builtin_amdgcn_global_load_lds((const __attribute__((address_space(1))) void*)gb,
                                       (__attribute__((address_space(3))) void*)lb, 16, 0, 0);
    }
    __syncthreads();
    short8 af[4], bfm[4];
    #pragma unroll
    for (int mi=0;mi<4;mi++) af[mi]  = *(const short8*)&As[(wm + mi*16 + fr)*32 + fq*8];
    #pragma unroll
    for (int ni=0;ni<4;ni++) bfm[ni] = *(const short8*)&Bs[(wn + ni*16 + fr)*32 + fq*8];
    #pragma unroll
    for (int mi=0;mi<4;mi++)
      #pragma unroll
      for (int ni=0;ni<4;ni++)
        acc[mi][ni] = __builtin_amdgcn_mfma_f32_16x16x32_bf16(af[mi], bfm[ni], acc[mi][ni], 0, 0, 0);
    __syncthreads();
  }

  #pragma unroll
  for (int mi=0;mi<4;mi++){
    #pragma unroll
    for (int ni=0;ni<4;ni++){
      int r0 = bm*128 + wm + mi*16 + fq*4;
      int c0 = bn*128 + wn + ni*16 + fr;
      #pragma unroll
      for (int rr=0;rr<4;rr++)
        C[(size_t)(r0+rr)*N + c0] = f2bf(acc[mi][ni][rr]);
    }
  }
}

// ---------------------------------------------------------------------------
// GEMM variant 2: A f32 (cvt to bf16 during LDS staging), Bt bf16, C bf16.
// ---------------------------------------------------------------------------
__global__ __launch_bounds__(256)
void gemm_f32a_bt(const float* __restrict__ A, const u16* __restrict__ Bt, u16* __restrict__ C,
                  int M, int N, int K)
{
  __shared__ __align__(16) u16 As[128*32];
  __shared__ __align__(16) u16 Bs[128*32];
  const int tid  = threadIdx.x;
  const int wave = tid >> 6;
  const int lane = tid & 63;
  const int bm = blockIdx.y, bn = blockIdx.x;
  const int fr = lane & 15, fq = lane >> 4;
  const int wm = (wave >> 1) * 64, wn = (wave & 1) * 64;
  const int srow = tid >> 2, spart = tid & 3;
  const float* Abase = A + (size_t)bm * 128 * K;
  const u16*   Bbase = Bt + (size_t)bn * 128 * K;

  f32x4v acc[4][4];
  #pragma unroll
  for (int i=0;i<4;i++)
    #pragma unroll
    for (int j=0;j<4;j++){ f32x4v z = {0.f,0.f,0.f,0.f}; acc[i][j] = z; }

  for (int k0 = 0; k0 < K; k0 += 32){
    #pragma unroll
    for (int c = 0; c < 2; ++c){
      const u16* gb = Bbase + (size_t)(c*64 + srow) * K + k0 + spart*8;
      u16* lb = &Bs[(c*64 + wave*16) * 32];
      __builtin_amdgcn_global_load_lds((const __attribute__((address_space(1))) void*)gb,
                                       (__attribute__((address_space(3))) void*)lb, 16, 0, 0);
      const float4* ga = (const float4*)(Abase + (size_t)(c*64 + srow) * K + k0 + spart*8);
      float4 v0 = ga[0], v1 = ga[1];
      uint4 pk;
      pk.x = pack2(v0.x, v0.y); pk.y = pack2(v0.z, v0.w);
      pk.z = pack2(v1.x, v1.y); pk.w = pack2(v1.z, v1.w);
      *(uint4*)&As[(c*64 + srow)*32 + spart*8] = pk;
    }
    __syncthreads();
    short8 af[4], bfm[4];
    #pragma unroll
    for (int mi=0;mi<4;mi++) af[mi]  = *(const short8*)&As[(wm + mi*16 + fr)*32 + fq*8];
    #pragma unroll
    for (int ni=0;ni<4;ni++) bfm[ni] = *(const short8*)&Bs[(wn + ni*16 + fr)*32 + fq*8];
    #pragma unroll
    for (int mi=0;mi<4;mi++)
      #pragma unroll
      for (int ni=0;ni<4;ni++)
        acc[mi][ni] = __builtin_amdgcn_mfma_f32_16x16x32_bf16(af[mi], bfm[ni], acc[mi][ni], 0, 0, 0);
    __syncthreads();
  }

  #pragma unroll
  for (int mi=0;mi<4;mi++){
    #pragma unroll
    for (int ni=0;ni<4;ni++){
      int r0 = bm*128 + wm + mi*16 + fq*4;
      int c0 = bn*128 + wn + ni*16 + fr;
      #pragma unroll
      for (int rr=0;rr<4;rr++)
        C[(size_t)(r0+rr)*N + c0] = f2bf(acc[mi][ni][rr]);
    }
  }
}

// ---------------------------------------------------------------------------
// GEMM variant 3: A bf16, Bt bf16, C f32 (final output projection).
// ---------------------------------------------------------------------------
__global__ __launch_bounds__(256)
void gemm_bt_f32out(const u16* __restrict__ A, const u16* __restrict__ Bt, float* __restrict__ C,
                    int M, int N, int K)
{
  __shared__ __align__(16) u16 As[128*32];
  __shared__ __align__(16) u16 Bs[128*32];
  const int tid  = threadIdx.x;
  const int wave = tid >> 6;
  const int lane = tid & 63;
  const int bm = blockIdx.y, bn = blockIdx.x;
  const int fr = lane & 15, fq = lane >> 4;
  const int wm = (wave >> 1) * 64, wn = (wave & 1) * 64;
  const int srow = tid >> 2, spart = tid & 3;
  const u16* Abase = A  + (size_t)bm * 128 * K;
  const u16* Bbase = Bt + (size_t)bn * 128 * K;

  f32x4v acc[4][4];
  #pragma unroll
  for (int i=0;i<4;i++)
    #pragma unroll
    for (int j=0;j<4;j++){ f32x4v z = {0.f,0.f,0.f,0.f}; acc[i][j] = z; }

  for (int k0 = 0; k0 < K; k0 += 32){
    #pragma unroll
    for (int c = 0; c < 2; ++c){
      const u16* ga = Abase + (size_t)(c*64 + srow) * K + k0 + spart*8;
      const u16* gb = Bbase + (size_t)(c*64 + srow) * K + k0 + spart*8;
      u16* la = &As[(c*64 + wave*16) * 32];
      u16* lb = &Bs[(c*64 + wave*16) * 32];
      __builtin_amdgcn_global_load_lds((const __attribute__((address_space(1))) void*)ga,
                                       (__attribute__((address_space(3))) void*)la, 16, 0, 0);
      __builtin_amdgcn_global_load_lds((const __attribute__((address_space(1))) void*)gb,
                                       (__attribute__((address_space(3))) void*)lb, 16, 0, 0);
    }
    __syncthreads();
    short8 af[4], bfm[4];
    #pragma unroll
    for (int mi=0;mi<4;mi++) af[mi]  = *(const short8*)&As[(wm + mi*16 + fr)*32 + fq*8];
    #pragma unroll
    for (int ni=0;ni<4;ni++) bfm[ni] = *(const short8*)&Bs[(wn + ni*16 + fr)*32 + fq*8];
    #pragma unroll
    for (int mi=0;mi<4;mi++)
      #pragma unroll
      for (int ni=0;ni<4;ni++)
        acc[mi][ni] = __builtin_amdgcn_mfma_f32_16x16x32_bf16(af[mi], bfm[ni], acc[mi][ni], 0, 0, 0);
    __syncthreads();
  }

  #pragma unroll
  for (int mi=0;mi<4;mi++){
    #pragma unroll
    for (int ni=0;ni<4;ni++){
      int r0 = bm*128 + wm + mi*16 + fq*4;
      int c0 = bn*128 + wn + ni*16 + fr;
      #pragma unroll
      for (int rr=0;rr<4;rr++)
        C[(size_t)(r0+rr)*N + c0] = acc[mi][ni][rr];
    }
  }
}

// ---------------------------------------------------------------------------
// Wa/Wb projections (N=6) + softplus/sigmoid -> g_decay, beta. All f32 in.
// ---------------------------------------------------------------------------
__global__ __launch_bounds__(64)
void proj_ab(const float* __restrict__ hs, const float* __restrict__ Wa, const float* __restrict__ Wb,
             const float* __restrict__ A_log, const float* __restrict__ dt_b,
             float* __restrict__ gdec, float* __restrict__ betav)
{
  int r = blockIdx.x;
  int lane = threadIdx.x;
  float hv[32];
  const float4* hp = (const float4*)(hs + (size_t)r*HID + lane*32);
  #pragma unroll
  for (int q=0;q<8;q++){ float4 v = hp[q]; hv[q*4]=v.x; hv[q*4+1]=v.y; hv[q*4+2]=v.z; hv[q*4+3]=v.w; }
  float a[6] = {0,0,0,0,0,0}, b[6] = {0,0,0,0,0,0};
  {
    const float* wp = Wa + (size_t)lane*192;
    #pragma unroll
    for (int u=0; u<48; ++u){
      float4 wv = *(const float4*)(wp + u*4);
      float wf[4] = {wv.x, wv.y, wv.z, wv.w};
      #pragma unroll
      for (int p=0;p<4;p++){ int idx = u*4+p; a[idx%6] += hv[idx/6] * wf[p]; }
    }
  }
  {
    const float* wp = Wb + (size_t)lane*192;
    #pragma unroll
    for (int u=0; u<48; ++u){
      float4 wv = *(const float4*)(wp + u*4);
      float wf[4] = {wv.x, wv.y, wv.z, wv.w};
      #pragma unroll
      for (int p=0;p<4;p++){ int idx = u*4+p; b[idx%6] += hv[idx/6] * wf[p]; }
    }
  }
  #pragma unroll
  for (int off=1; off<64; off<<=1){
    #pragma unroll
    for (int j=0;j<6;j++){ a[j] += __shfl_xor(a[j], off); b[j] += __shfl_xor(b[j], off); }
  }
  if (lane == 0){
    #pragma unroll
    for (int j=0;j<6;j++){
      float da = a[j] + dt_b[j];
      float sp = (da > 15.f) ? da : log1pf(expf(da));
      gdec[(size_t)r*6 + j]  = -expf(A_log[j]) * sp;
      betav[(size_t)r*6 + j] = 1.f / (1.f + expf(-b[j]));
    }
  }
}

// ---------------------------------------------------------------------------
// Causal conv(K=4)+SiLU + per-head l2norm (q: scale=1/16, k: 1).
// ---------------------------------------------------------------------------
__global__ __launch_bounds__(256)
void conv_norm_qk(const u16* __restrict__ x, const float* __restrict__ cw,
                  u16* __restrict__ outp, float scale)
{
  int r = blockIdx.x, h = blockIdx.y;
  int t = r & (T_-1);
  int d = threadIdx.x;
  int colg = h*DK + d;
  float4 wv = *(const float4*)(cw + (size_t)colg*4);
  float w[4] = {wv.x, wv.y, wv.z, wv.w};
  float acc = 0.f;
  #pragma unroll
  for (int i=0;i<4;i++){
    int st = t - 3 + i;
    if (st >= 0) acc += bf2f(x[(size_t)(r-3+i)*KD + colg]) * w[i];
  }
  float yv = acc / (1.f + __expf(-acc));
  float ss = yv*yv;
  #pragma unroll
  for (int off=1; off<64; off<<=1) ss += __shfl_xor(ss, off);
  __shared__ float red[4];
  if ((threadIdx.x & 63) == 0) red[threadIdx.x>>6] = ss;
  __syncthreads();
  float tot = red[0]+red[1]+red[2]+red[3];
  float out = yv * rsqrtf(tot) * scale;
  outp[(size_t)r*KD + colg] = f2bf(out);
}

// ---------------------------------------------------------------------------
// Causal conv(K=4)+SiLU for v.
// ---------------------------------------------------------------------------
__global__ __launch_bounds__(384)
void conv_v_k(const u16* __restrict__ x, const float* __restrict__ cw, u16* __restrict__ outp)
{
  int r = blockIdx.x;
  int t = r & (T_-1);
  int c8 = threadIdx.x * 8;
  float w[8][4];
  #pragma unroll
  for (int q=0;q<8;q++){
    float4 wv = *(const float4*)(cw + (size_t)c8*4 + q*4);
    w[q][0]=wv.x; w[q][1]=wv.y; w[q][2]=wv.z; w[q][3]=wv.w;
  }
  float acc[8] = {0,0,0,0,0,0,0,0};
  #pragma unroll
  for (int i=0;i<4;i++){
    int st = t-3+i;
    if (st >= 0){
      uint4 xv = *(const uint4*)(x + (size_t)(r-3+i)*VD + c8);
      float xf[8]; unpack8(xv, xf);
      #pragma unroll
      for (int e=0;e<8;e++) acc[e] += xf[e]*w[e][i];
    }
  }
  u32 pk[4];
  #pragma unroll
  for (int e=0;e<8;e+=2){
    float y0 = acc[e]  /(1.f+__expf(-acc[e]));
    float y1 = acc[e+1]/(1.f+__expf(-acc[e+1]));
    pk[e/2] = pack2(y0, y1);
  }
  uint4 o4; o4.x=pk[0]; o4.y=pk[1]; o4.z=pk[2]; o4.w=pk[3];
  *(uint4*)(outp + (size_t)r*VD + c8) = o4;
}

// ---------------------------------------------------------------------------
// Gated delta rule scan v2 — no LDS, no barriers, register prefetch.
// Grid (32 dv-slices, NH, B_) = 384 blocks, block 256 (4 waves).
// Thread (col = tid>>4 of 16 cols, rg = tid&15) owns S[dk rows rg*16..+15]
// of dv column (slice*16+col). k/q read as 2x16B coalesced global loads
// (16 lanes cover 256 dk contiguous; 4 col-groups/wave are duplicate
// addresses -> coalesced). pred/o reductions: 4 xor-shuffles over 16 lanes.
// Next token's k/q/v/g/beta prefetched into registers before this token's
// dependency chain so global latency overlaps the serial recurrence.
// ---------------------------------------------------------------------------
__global__ __launch_bounds__(256)
void scan_k2(const u16* __restrict__ qc, const u16* __restrict__ kc, const u16* __restrict__ vc,
             const float* __restrict__ gdec, const float* __restrict__ betav,
             u16* __restrict__ o)
{
  const int slice = blockIdx.x, h = blockIdx.y, b = blockIdx.z;
  const int tid = threadIdx.x;
  const int col = tid >> 4;            // 0..15
  const int rg  = tid & 15;            // 0..15
  const int colg = h*DV + slice*16 + col;
  const size_t rb = (size_t)b * T_;
  const size_t kqoff = (size_t)h*DK + rg*16;

  float S[16];
  #pragma unroll
  for (int i=0;i<16;i++) S[i] = 0.f;

  // prefetch token 0
  uint4 kva = *(const uint4*)(kc + rb*KD + kqoff);
  uint4 kvb = *(const uint4*)(kc + rb*KD + kqoff + 8);
  uint4 qva = *(const uint4*)(qc + rb*KD + kqoff);
  uint4 qvb = *(const uint4*)(qc + rb*KD + kqoff + 8);
  u16   vraw = vc[rb*VD + colg];
  float gg  = gdec[rb*6 + h];
  float bb  = betav[rb*6 + h];

  for (int t = 0; t < T_; ++t){
    // unpack current token
    float kf[16], qf[16];
    unpack8(kva, kf); unpack8(kvb, kf+8);
    unpack8(qva, qf); unpack8(qvb, qf+8);
    float vv    = bf2f(vraw);
    float decay = __expf(gg);
    float bta   = bb;

    // prefetch next token (clamped; redundant final reload is harmless)
    int tn = (t+1 < T_) ? (t+1) : t;
    size_t rn = rb + tn;
    kva = *(const uint4*)(kc + rn*KD + kqoff);
    kvb = *(const uint4*)(kc + rn*KD + kqoff + 8);
    qva = *(const uint4*)(qc + rn*KD + kqoff);
    qvb = *(const uint4*)(qc + rn*KD + kqoff + 8);
    vraw = vc[rn*VD + colg];
    gg  = gdec[rn*6 + h];
    bb  = betav[rn*6 + h];

    // pred = k . S_old (then scaled by decay)
    float p0 = 0.f, p1 = 0.f;
    #pragma unroll
    for (int i=0;i<8;i++){
      p0 = fmaf(kf[i],   S[i],   p0);
      p1 = fmaf(kf[i+8], S[i+8], p1);
    }
    float p = p0 + p1;
    p += __shfl_xor(p, 1); p += __shfl_xor(p, 2);
    p += __shfl_xor(p, 4); p += __shfl_xor(p, 8);

    float delta = (vv - decay * p) * bta;

    // S = decay*S + k*delta ; oo = q . S
    float o0 = 0.f, o1 = 0.f;
    #pragma unroll
    for (int i=0;i<8;i++){
      S[i]   = fmaf(S[i],   decay, kf[i]   * delta);
      S[i+8] = fmaf(S[i+8], decay, kf[i+8] * delta);
      o0 = fmaf(qf[i],   S[i],   o0);
      o1 = fmaf(qf[i+8], S[i+8], o1);
    }
    float oo = o0 + o1;
    oo += __shfl_xor(oo, 1); oo += __shfl_xor(oo, 2);
    oo += __shfl_xor(oo, 4); oo += __shfl_xor(oo, 8);

    if (rg == 0)
      o[(rb + t)*VD + colg] = f2bf(oo);
  }
}

// ---------------------------------------------------------------------------
// RMSNorm(512) * norm_weight(f32) * silu(gate) -> y bf16. Grid (MROWS, NH).
// ---------------------------------------------------------------------------
__global__ __launch_bounds__(256)
void norm_gate_k(const u16* __restrict__ o, const u16* __restrict__ gate,
                 const float* __restrict__ nw, u16* __restrict__ y)
{
  int r = blockIdx.x, h = blockIdx.y;
  size_t base = (size_t)r*VD + h*DV;
  int e = threadIdx.x * 2;
  u32 opair = *(const u32*)(o + base + e);
  float ox = bf2f((u16)(opair & 0xffffu)), oy = bf2f((u16)(opair >> 16));
  float ss = ox*ox + oy*oy;
  #pragma unroll
  for (int off=1; off<64; off<<=1) ss += __shfl_xor(ss, off);
  __shared__ float red[4];
  if ((threadIdx.x & 63) == 0) red[threadIdx.x>>6] = ss;
  __syncthreads();
  float ms = (red[0]+red[1]+red[2]+red[3]) * (1.f/512.f);
  float sc = rsqrtf(ms + 1e-5f);
  u32 gv = *(const u32*)(gate + base + e);
  float g0 = bf2f((u16)(gv & 0xffffu)), g1 = bf2f((u16)(gv >> 16));
  float s0 = g0 / (1.f + __expf(-g0)), s1 = g1 / (1.f + __expf(-g1));
  float y0 = ox * sc * nw[e]   * s0;
  float y1 = oy * sc * nw[e+1] * s1;
  *(u32*)(y + base + e) = pack2(y0, y1);
}

// ---------------------------------------------------------------------------
// Workspace plan (163.9 MB; regions reused):
//   WT   12.58 MB : transposed+downcast weight (reused 5x, stream-serial)
//   bufA 50.33 MB : q_lin | k_lin  ->  vcp  ->  y
//   bufB 50.33 MB : v_lin          ->  op (bf16)
//   bufC 50.33 MB : qc | kc        ->  gatep
//   gdec/betav 0.4 MB
// ---------------------------------------------------------------------------
extern "C" void kernel_launch(void* const* d_in, const int* in_sizes, int n_in,
                              void* d_out, int out_size, void* d_ws, size_t ws_size,
                              hipStream_t stream)
{
  const float* hs    = (const float*)d_in[0];
  const float* Wq    = (const float*)d_in[1];
  const float* Wk    = (const float*)d_in[2];
  const float* Wv    = (const float*)d_in[3];
  const float* Wa    = (const float*)d_in[4];
  const float* Wb    = (const float*)d_in[5];
  const float* Wg    = (const float*)d_in[6];
  const float* Wo    = (const float*)d_in[7];
  const float* cwq   = (const float*)d_in[8];
  const float* cwk   = (const float*)d_in[9];
  const float* cwv   = (const float*)d_in[10];
  const float* A_log = (const float*)d_in[11];
  const float* dt_b  = (const float*)d_in[12];
  const float* nw    = (const float*)d_in[13];
  float* out = (float*)d_out;

  char* wsb = (char*)d_ws;
  size_t off = 0;
  auto alloc = [&](size_t bytes)->char* {
    char* p = wsb + off; off += (bytes + 255) & ~(size_t)255; return p;
  };
  u16* WT   = (u16*)alloc((size_t)HID*VD*2);
  u16* bufA = (u16*)alloc((size_t)MROWS*VD*2);
  u16* bufB = (u16*)alloc((size_t)MROWS*VD*2);
  u16* bufC = (u16*)alloc((size_t)MROWS*VD*2);
  float* gdec  = (float*)alloc((size_t)MROWS*NH*4);
  float* betav = (float*)alloc((size_t)MROWS*NH*4);

  u16* q_lin = bufA;
  u16* k_lin = bufA + (size_t)MROWS*KD;
  u16* v_lin = bufB;
  u16* qc    = bufC;
  u16* kc    = bufC + (size_t)MROWS*KD;
  u16* vcp   = bufA;          // after q/k convs consume q_lin/k_lin
  u16* op    = bufB;          // after v conv consumes v_lin
  u16* gatep = bufC;          // after scan consumes qc/kc
  u16* yp    = bufA;          // after scan consumes vcp

  dim3 blk256(256);

  // q projection
  transpose_f2b<<<dim3(KD/64, HID/64), blk256, 0, stream>>>(Wq, WT, HID, KD);
  gemm_f32a_bt<<<dim3(KD/128, MROWS/128), blk256, 0, stream>>>(hs, WT, q_lin, MROWS, KD, HID);
  // k projection
  transpose_f2b<<<dim3(KD/64, HID/64), blk256, 0, stream>>>(Wk, WT, HID, KD);
  gemm_f32a_bt<<<dim3(KD/128, MROWS/128), blk256, 0, stream>>>(hs, WT, k_lin, MROWS, KD, HID);
  // v projection
  transpose_f2b<<<dim3(VD/64, HID/64), blk256, 0, stream>>>(Wv, WT, HID, VD);
  gemm_f32a_bt<<<dim3(VD/128, MROWS/128), blk256, 0, stream>>>(hs, WT, v_lin, MROWS, VD, HID);
  // a/b projections + activations
  proj_ab<<<dim3(MROWS), dim3(64), 0, stream>>>(hs, Wa, Wb, A_log, dt_b, gdec, betav);

  // convs (+ l2norm for q/k; q also * dk^-0.5). q,k before v (vcp overwrites bufA).
  conv_norm_qk<<<dim3(MROWS, NH), blk256, 0, stream>>>(q_lin, cwq, qc, 0.0625f);
  conv_norm_qk<<<dim3(MROWS, NH), blk256, 0, stream>>>(k_lin, cwk, kc, 1.0f);
  conv_v_k<<<dim3(MROWS), dim3(384), 0, stream>>>(v_lin, cwv, vcp);

  // gated delta rule scan v2 -> op (bf16, overwrites v_lin region)
  scan_k2<<<dim3(32, NH, B_), blk256, 0, stream>>>(qc, kc, vcp, gdec, betav, op);

  // gate projection (into bufC, now free)
  transpose_f2b<<<dim3(VD/64, HID/64), blk256, 0, stream>>>(Wg, WT, HID, VD);
  gemm_f32a_bt<<<dim3(VD/128, MROWS/128), blk256, 0, stream>>>(hs, WT, gatep, MROWS, VD, HID);

  // RMSNorm * nw * silu(gate) -> y (into bufA, now free)
  norm_gate_k<<<dim3(MROWS, NH), blk256, 0, stream>>>(op, gatep, nw, yp);

  // output projection: out(f32) = y @ Wo  (Wo [VD][HID] -> WoT [HID][VD])
  transpose_f2b<<<dim3(HID/64, VD/64), blk256, 0, stream>>>(Wo, WT, VD, HID);
  gemm_bt_f32out<<<dim3(HID/128, MROWS/128), blk256, 0, stream>>>(yp, WT, out, MROWS, HID, VD);
}